// Round 7
// baseline (170.412 us; speedup 1.0000x reference)
//
#include <hip/hip_runtime.h>
#include <stdint.h>

// MipRayMarcher2: NeuS-style alpha compositing.
// R7: counted-vmcnt persistent pipeline with a ZERO-compiler-vmem loop.
//
// R3's pipeline was silently broken: dir loads + per-tile stores inside the
// loop made the compiler insert its own vmcnt waits (one shared counter),
// collapsing the counted-vmcnt scheme to per-tile drains. Fix (m201-style):
//  - dirs preloaded to registers before the loop (pin forces completion),
//  - ALL stores deferred to after the loop (outputs accumulate in regs:
//    3 weights/thread/tile + 1 distributed epilogue scalar -> 32 VGPR),
//  - loop body: issue DMA(i+1) -> s_waitcnt vmcnt(9/6) [exact: vmcnt retires
//    in order (m135) and the queue holds ONLY D(i),D(i+1)] -> barrier ->
//    compute from LDS -> barrier. Never drains to 0 in steady state; each
//    block keeps ~33 KB posted continuously (T3/T4, +38-73% on GEMM m218).

static constexpr int NRAYS = 65536;          // B*R = 4*16384
static constexpr int SM = 47;
static constexpr int OFF_DEPTH  = NRAYS * 3;             // 196608
static constexpr int OFF_W      = OFF_DEPTH + NRAYS;     // 262144
static constexpr int OFF_NORMAL = OFF_W + NRAYS * SM;    // 3342336

static constexpr int TILES   = 8;            // tiles of 16 rays per block
static constexpr int NBLOCKS = 512;          // 512*8*16 = 65536 rays; 2 blocks/CU

// Per-buffer LDS layout (bytes): colors/normals/reals 9216 B each,
// sdf/depth 3072 B each -> 33792 B per buffer, two buffers.
static constexpr int LB_COL = 0;
static constexpr int LB_NRM = 9216;
static constexpr int LB_RNM = 18432;
static constexpr int LB_SDF = 27648;
static constexpr int LB_DEP = 30720;
static constexpr int LDS_BYTES = 33792;
static constexpr int LF_COL = 0;
static constexpr int LF_NRM = 2304;
static constexpr int LF_RNM = 4608;
static constexpr int LF_SDF = 6912;
static constexpr int LF_DEP = 7680;

struct F3 { float x, y, z; };

template <int CTRL>
__device__ __forceinline__ float dpp_mov(float x, float old) {
    return __builtin_bit_cast(float,
        __builtin_amdgcn_update_dpp(__builtin_bit_cast(int, old),
                                    __builtin_bit_cast(int, x),
                                    CTRL, 0xF, 0xF, false));
}
#define ROW_SHR(n) (0x110 + (n))
#define ROW_ROR(n) (0x120 + (n))

// Sum across the 16-lane row; all lanes end with the total.
__device__ __forceinline__ float row_sum16(float x) {
    x += dpp_mov<ROW_ROR(8)>(x, 0.0f);
    x += dpp_mov<ROW_ROR(4)>(x, 0.0f);
    x += dpp_mov<ROW_ROR(2)>(x, 0.0f);
    x += dpp_mov<ROW_ROR(1)>(x, 0.0f);
    return x;
}

// Async DMA: 64 lanes x 16 B = 1 KB, global -> LDS (wave-uniform base +
// lane*16). No destination VGPRs; counts on vmcnt, retires in order.
__device__ __forceinline__ void dma16(char* lds_base, uint32_t lds_off, const char* g) {
    __builtin_amdgcn_global_load_lds(
        (const __attribute__((address_space(1))) void*)g,
        (__attribute__((address_space(3))) void*)(lds_base + lds_off),
        16, 0, 0);
}

__global__ __launch_bounds__(256, 2) void march_kernel(
    const float* __restrict__ colors,
    const float* __restrict__ sdfs,
    const float* __restrict__ depths,
    const float* __restrict__ normals,
    const float* __restrict__ ray_dirs,
    const float* __restrict__ real_normals,
    const float* __restrict__ inv_std_p,
    float* __restrict__ out)
{
    __shared__ __align__(16) char smem[2 * LDS_BYTES];

    const int t    = threadIdx.x;
    const int w    = t >> 6;            // wave id 0..3
    const int lane = t & 63;
    const int g16  = t >> 4;            // ray group within tile (DPP row)
    const int sl   = t & 15;            // sub-lane within ray group

    const int tile0 = blockIdx.x * TILES;
    const uint32_t lo16 = (uint32_t)lane * 16u;

    // Wave-uniform constants.
    const float L2E = 1.4426950408889634f;
    const float inv_std = fminf(fmaxf(__expf(inv_std_p[0] * 10.0f), 1e-6f), 1e6f);
    const float uu = inv_std * (0.5f  * L2E);
    const float qq = inv_std * (0.25f * L2E);

    // Preload ALL ray directions for this block's 8 tiles; the pin consumes
    // the values so their loads complete HERE -> no compiler vmem (and no
    // compiler waitcnts) inside the pipelined loop.
    F3 dirs[TILES];
#pragma unroll
    for (int i = 0; i < TILES; ++i)
        dirs[i] = ((const F3*)ray_dirs)[(tile0 + i) * 16 + g16];
#pragma unroll
    for (int i = 0; i < TILES; ++i)
        asm volatile("" :: "v"(dirs[i].x), "v"(dirs[i].y), "v"(dirs[i].z));

    // Issue all DMA chunks for tile (tile0+i) into buffer bsel.
    auto issue = [&](int i, int bsel) {
        char* dst = smem + bsel * LDS_BYTES;
        const size_t r0 = (size_t)(tile0 + i) * 16;
        if (w == 0) {
            const char* s = (const char*)colors + r0 * 576 + lo16;
#pragma unroll
            for (int k = 0; k < 9; ++k) dma16(dst, LB_COL + k * 1024, s + k * 1024);
        } else if (w == 1) {
            const char* s = (const char*)normals + r0 * 576 + lo16;
#pragma unroll
            for (int k = 0; k < 9; ++k) dma16(dst, LB_NRM + k * 1024, s + k * 1024);
        } else if (w == 2) {
            const char* s = (const char*)real_normals + r0 * 576 + lo16;
#pragma unroll
            for (int k = 0; k < 9; ++k) dma16(dst, LB_RNM + k * 1024, s + k * 1024);
        } else {
            const char* s1 = (const char*)sdfs   + r0 * 192 + lo16;
            const char* s2 = (const char*)depths + r0 * 192 + lo16;
#pragma unroll
            for (int k = 0; k < 3; ++k) dma16(dst, LB_SDF + k * 1024, s1 + k * 1024);
#pragma unroll
            for (int k = 0; k < 3; ++k) dma16(dst, LB_DEP + k * 1024, s2 + k * 1024);
        }
    };

    issue(0, 0);   // prologue: tile 0 in flight

    // Per-tile outputs accumulated in registers (static indices, rule #20).
    float wq0[TILES], wq1[TILES], wq2[TILES], ep[TILES];

#pragma unroll
    for (int i = 0; i < TILES; ++i) {
        const int b = i & 1;

        if (i + 1 < TILES) {
            issue(i + 1, b ^ 1);   // buf[b^1] free: barrier at end of iter i-1
            // Exact counted wait: vmcnt queue = [D(i), D(i+1)], in-order
            // retirement -> "<= n_new outstanding" proves D(i) complete.
            if (w == 3) asm volatile("s_waitcnt vmcnt(6)" ::: "memory");
            else        asm volatile("s_waitcnt vmcnt(9)" ::: "memory");
        } else {
            asm volatile("s_waitcnt vmcnt(0)" ::: "memory");
        }
        __builtin_amdgcn_s_barrier();       // all waves certified tile-i data
        asm volatile("" ::: "memory");      // no LDS read hoists above

        // ---------------- compute tile i from buffer b ----------------
        const float* sf = (const float*)(smem + b * LDS_BYTES);
        const int cfb = g16 * 144 + sl * 9;
        const int sfb = g16 * 48  + sl * 3;

        float SD[4], DP[4];
#pragma unroll
        for (int c2 = 0; c2 < 4; ++c2) SD[c2] = sf[LF_SDF + sfb + c2];
#pragma unroll
        for (int c2 = 0; c2 < 3; ++c2) DP[c2] = sf[LF_DEP + sfb + c2];
        // (g16==15, sl==15): +3 would read 1 float past the buffer: clamp
        // (value masked; avoids poisoning sdp with uninitialized LDS).
        DP[3] = sf[LF_DEP + sfb + (((sl < 15) | (g16 < 15)) ? 3 : 2)];

        float C[12], N[12], R[12];
#pragma unroll
        for (int q = 0; q < 12; ++q) {
            C[q] = sf[LF_COL + cfb + q];
            N[q] = sf[LF_NRM + cfb + q];
            R[q] = sf[LF_RNM + cfb + q];
        }

        float al[3], tt[3], dsum[3];
#pragma unroll
        for (int j = 0; j < 3; ++j) {
            const float delta = DP[j + 1] - DP[j];
            dsum[j] = DP[j] + DP[j + 1];
            const float ss  = SD[j] + SD[j + 1];
            const float ns0 = N[j * 3 + 0] + N[j * 3 + 3];
            const float ns1 = N[j * 3 + 1] + N[j * 3 + 4];
            const float ns2 = N[j * 3 + 2] + N[j * 3 + 5];

            const float dots = dirs[i].x * ns0 + dirs[i].y * ns1 + dirs[i].z * ns2;
            const float mn   = fminf(dots, 0.0f);
            const float mq   = mn * delta * qq;
            const float base = ss * uu;
            const float epx = __builtin_amdgcn_exp2f(mq - base);
            const float pc  = __builtin_amdgcn_rcpf(1.0f + epx);
            const float en  = __builtin_amdgcn_exp2f(-(mq + base));
            const float nc  = __builtin_amdgcn_rcpf(1.0f + en);

            float a = (pc - nc + 1e-5f) * __builtin_amdgcn_rcpf(pc + 1e-5f);
            a = fminf(fmaxf(a, 0.0f), 1.0f);
            const bool valid = (j < 2) | (sl < 15);   // interval 47 absent
            if (!valid) a = 0.0f;
            al[j] = a;
            tt[j] = 1.0f - a + 1e-10f;
        }

        // Inclusive multiply-scan over the row (DPP, identity=1).
        float p = tt[0] * tt[1] * tt[2];
        p *= dpp_mov<ROW_SHR(1)>(p, 1.0f);
        p *= dpp_mov<ROW_SHR(2)>(p, 1.0f);
        p *= dpp_mov<ROW_SHR(4)>(p, 1.0f);
        p *= dpp_mov<ROW_SHR(8)>(p, 1.0f);
        const float excl = dpp_mov<ROW_SHR(1)>(p, 1.0f);   // lane 0 -> 1.0

        const float T0 = excl;
        const float T1 = excl * tt[0];
        const float T2 = T1 * tt[1];
        const float w0 = al[0] * T0;
        const float w1 = al[1] * T1;
        const float w2 = al[2] * T2;
        wq0[i] = w0; wq1[i] = w1; wq2[i] = w2;

        float ws  = w0 + w1 + w2;
        float sc0 = w0 * (C[0] + C[3]) + w1 * (C[3] + C[6]) + w2 * (C[6] + C[9]);
        float sc1 = w0 * (C[1] + C[4]) + w1 * (C[4] + C[7]) + w2 * (C[7] + C[10]);
        float sc2 = w0 * (C[2] + C[5]) + w1 * (C[5] + C[8]) + w2 * (C[8] + C[11]);
        float sdp = w0 * dsum[0] + w1 * dsum[1] + w2 * dsum[2];
        float sr0 = w0 * (R[0] + R[3]) + w1 * (R[3] + R[6]) + w2 * (R[6] + R[9]);
        float sr1 = w0 * (R[1] + R[4]) + w1 * (R[4] + R[7]) + w2 * (R[7] + R[10]);
        float sr2 = w0 * (R[2] + R[5]) + w1 * (R[5] + R[8]) + w2 * (R[8] + R[11]);

        ws  = row_sum16(ws);
        sc0 = row_sum16(sc0);
        sc1 = row_sum16(sc1);
        sc2 = row_sum16(sc2);
        sdp = row_sum16(sdp);
        sr0 = row_sum16(sr0);
        sr1 = row_sum16(sr1);
        sr2 = row_sum16(sr2);

        // Distributed epilogue scalar: lane sl keeps value sl (all lanes hold
        // all sums after row_sum16). Stored after the loop.
        const float hiw = 0.5f * __builtin_amdgcn_rcpf(ws);  // ws >= ~5e-6
        ep[i] = (sl == 0) ? 0.5f * sc0
              : (sl == 1) ? 0.5f * sc1
              : (sl == 2) ? 0.5f * sc2
              : (sl == 3) ? sdp * hiw
              : (sl == 4) ? sr0 * hiw
              : (sl == 5) ? sr1 * hiw
              : (sl == 6) ? sr2 * hiw
              : 0.0f;

        // All waves done reading buf[b] before iter i+1 DMAs into it.
        asm volatile("s_waitcnt lgkmcnt(0)" ::: "memory");
        __builtin_amdgcn_s_barrier();
        asm volatile("" ::: "memory");
    }

    // ---------------- deferred store phase (only vmem after the loop) ----------------
#pragma unroll
    for (int i = 0; i < TILES; ++i) {
        const int ray = (tile0 + i) * 16 + g16;
        const int wb  = OFF_W + ray * SM + sl * 3;
        out[wb + 0] = wq0[i];
        out[wb + 1] = wq1[i];
        if (sl < 15) out[wb + 2] = wq2[i];
        if (sl < 7) {
            const int addr = (sl < 3)  ? ray * 3 + sl
                           : (sl == 3) ? OFF_DEPTH + ray
                                       : OFF_NORMAL + ray * 3 + (sl - 4);
            out[addr] = ep[i];
        }
    }
}

extern "C" void kernel_launch(void* const* d_in, const int* in_sizes, int n_in,
                              void* d_out, int out_size, void* d_ws, size_t ws_size,
                              hipStream_t stream) {
    const float* colors       = (const float*)d_in[0];
    const float* sdfs         = (const float*)d_in[1];
    const float* depths       = (const float*)d_in[2];
    const float* normals      = (const float*)d_in[3];
    const float* ray_dirs     = (const float*)d_in[4];
    const float* real_normals = (const float*)d_in[5];
    const float* inv_std_p    = (const float*)d_in[6];
    float* out = (float*)d_out;

    dim3 grid(NBLOCKS);      // 512 blocks x 8 tiles x 16 rays = 65536 rays
    dim3 block(256);
    hipLaunchKernelGGL(march_kernel, grid, block, 0, stream,
                       colors, sdfs, depths, normals, ray_dirs, real_normals,
                       inv_std_p, out);
}